// Round 19
// baseline (348.100 us; speedup 1.0000x reference)
//
#include <hip/hip_runtime.h>
#include <hip/hip_fp16.h>

#define FDIM 256   // H*C = 4*64
#define NH 4

typedef float f32x4 __attribute__((ext_vector_type(4)));
typedef int   i32x4 __attribute__((ext_vector_type(4)));
typedef short short8v __attribute__((ext_vector_type(8)));
typedef unsigned short ushort_t;
typedef unsigned short ushort8 __attribute__((ext_vector_type(8)));

__device__ __forceinline__ float leaky02(float v) { return v > 0.0f ? v : 0.2f * v; }

__device__ __forceinline__ ushort_t f2bf(float f) {
    union { float f; unsigned int u; } v; v.f = f;
    unsigned int u = v.u + 0x7FFFu + ((v.u >> 16) & 1u);   // RNE
    return (ushort_t)(u >> 16);
}

__device__ __forceinline__ float bf2f(ushort_t u) {
    union { float f; unsigned int u; } v;
    v.u = ((unsigned int)u) << 16;
    return v.f;
}

__device__ __forceinline__ void gload_lds16(const void* g, void* lds) {
    __builtin_amdgcn_global_load_lds((const __attribute__((address_space(1))) unsigned int*)g,
                                     (__attribute__((address_space(3))) unsigned int*)lds, 16, 0, 0);
}

// unpack fp16 weight for head h from edge record
__device__ __forceinline__ float recw(const i32x4& r, int h) {
    unsigned v = (h < 2) ? (unsigned)r.y : (unsigned)r.z;
    unsigned bits = (h & 1) ? (v >> 16) : (v & 0xFFFFu);
    __half_raw hr; hr.x = (unsigned short)bits;
    return __half2float(*reinterpret_cast<__half*>(&hr));
}

// ---------------- K0: W (fp32 [256][256]) -> Wbf bf16 fragment-linear -------------
__global__ __launch_bounds__(256) void wprep_kernel(const float* __restrict__ W,
                                                    ushort_t* __restrict__ Wbf) {
    const int k = blockIdx.x;
    const int col = threadIdx.x;
    Wbf[(((size_t)(k >> 3) * 256 + col) << 3) + (k & 7)] = f2bf(W[(size_t)k * 256 + col]);
}

// ---------------- K1: x (fp32) -> xb (bf16 row-major) + hist/rank at tail ----------
__global__ __launch_bounds__(256) void xprep_kernel(const float* __restrict__ x,
                                                    ushort_t* __restrict__ xb, int n,
                                                    const int* __restrict__ dst,
                                                    int* __restrict__ counts,
                                                    ushort_t* __restrict__ rank, int E) {
    const int stride = gridDim.x * blockDim.x;
    const int gid = blockIdx.x * blockDim.x + threadIdx.x;
    const int total8 = n * 32;                 // groups of 8 floats
    for (int idx = gid; idx < total8; idx += stride) {
        const float4 v0 = ((const float4*)x)[(size_t)idx * 2];
        const float4 v1 = ((const float4*)x)[(size_t)idx * 2 + 1];
        ushort8 u;
        u[0]=f2bf(v0.x); u[1]=f2bf(v0.y); u[2]=f2bf(v0.z); u[3]=f2bf(v0.w);
        u[4]=f2bf(v1.x); u[5]=f2bf(v1.y); u[6]=f2bf(v1.z); u[7]=f2bf(v1.w);
        *(ushort8*)(xb + (size_t)idx * 8) = u;
    }
    for (int e = gid; e < E; e += stride) {
        const int d = __builtin_nontemporal_load(&dst[e]);
        rank[e] = (ushort_t)atomicAdd(&counts[d], 1);
    }
}

// ---------------- K2: xpb = bf16(xb @ W) — double-buffered gload_lds pipeline ------
// 512 threads (8 waves, wm=w>>2 in {0,1}, wn=w&3 = HEAD), BM=128, BN=256, BK=32.
// Per step: issue 24 gload_lds for s+1 into free buf, MFMA step s, ONE barrier.
__global__ __launch_bounds__(512) void gemm_xp_kernel(const ushort_t* __restrict__ xb,
                                                      const ushort_t* __restrict__ Wbf,
                                                      const float* __restrict__ att_s,
                                                      const float* __restrict__ att_d,
                                                      ushort_t* __restrict__ xpb,
                                                      float* __restrict__ a_src,
                                                      float* __restrict__ a_dst, int n) {
    __shared__ ushort_t a_lds[2][4096];   // 2 x 8 KB: [kb 0..3][row 0..127][8]
    __shared__ ushort_t b_lds[2][8192];   // 2 x 16 KB: [kb 0..3][col 0..255][8]
    const int t = threadIdx.x;
    const int w = t >> 6, l = t & 63;
    const int wm = w >> 2, wn = w & 3;
    const int row0 = blockIdx.x << 7;
    const int fr = l & 15, fk = l >> 4;

    const ushort_t* ptrA[2];
    #pragma unroll
    for (int rh = 0; rh < 2; ++rh) {
        int r = row0 + rh * 64 + l;
        if (r >= n) r = n - 1;
        ptrA[rh] = xb + (size_t)r * FDIM;
    }
    const ushort_t* ptrB = Wbf + ((size_t)l << 3);

    auto stage = [&](int s, int buf) {
        #pragma unroll
        for (int j = 0; j < 3; ++j) {
            const int c = w * 3 + j;   // 0..23, wave-uniform
            if (c < 8) {
                const int kb = c >> 1, rh = c & 1;
                gload_lds16(ptrA[rh] + s * 32 + kb * 8,
                            (char*)&a_lds[buf][0] + ((kb * 128 + rh * 64) << 4));
            } else {
                const int cc = c - 8;
                const int kb = cc >> 2, q = cc & 3;
                gload_lds16(ptrB + (((size_t)(s * 4 + kb) << 8) + q * 64) * 8,
                            (char*)&b_lds[buf][0] + ((kb * 256 + q * 64) << 4));
            }
        }
    };

    stage(0, 0);
    __syncthreads();               // prologue drain: buf0 ready

    f32x4 acc[4][4] = {};
    int buf = 0;
    for (int s = 0; s < 8; ++s) {
        if (s < 7) stage(s + 1, buf ^ 1);   // issue next-step loads (buf^1 free since
                                            // its readers finished before last barrier)
        short8v af[4], bfv[4];
        #pragma unroll
        for (int m = 0; m < 4; ++m)
            af[m] = *(const short8v*)&a_lds[buf][(((size_t)fk << 7) + wm * 64 + m * 16 + fr) << 3];
        #pragma unroll
        for (int nf = 0; nf < 4; ++nf)
            bfv[nf] = *(const short8v*)&b_lds[buf][(((size_t)fk << 8) + wn * 64 + nf * 16 + fr) << 3];
        #pragma unroll
        for (int m = 0; m < 4; ++m)
            #pragma unroll
            for (int nf = 0; nf < 4; ++nf)
                acc[m][nf] = __builtin_amdgcn_mfma_f32_16x16x32_bf16(af[m], bfv[nf], acc[m][nf], 0, 0, 0);
        __syncthreads();           // MFMA(s) work sits between stage-issue and this
                                   // drain -> latency hidden; also fences buf reuse
        buf ^= 1;
    }

    // ---- epilogue 1: bf16 store.  C/D: col=lane&15, row=(lane>>4)*4+j ----
    #pragma unroll
    for (int m = 0; m < 4; ++m) {
        const int r_ = row0 + wm * 64 + m * 16 + fk * 4;
        #pragma unroll
        for (int nf = 0; nf < 4; ++nf) {
            const int c_ = wn * 64 + nf * 16 + fr;
            #pragma unroll
            for (int j = 0; j < 4; ++j)
                if (r_ + j < n)
                    xpb[(size_t)(r_ + j) * FDIM + c_] = f2bf(acc[m][nf][j]);
        }
    }

    // ---- epilogue 2: fused fp32 attention dots (wave wn == head wn) ----
    float att_sv[4], att_dv[4];
    #pragma unroll
    for (int nf = 0; nf < 4; ++nf) {
        att_sv[nf] = att_s[(wn << 6) + (nf << 4) + fr];
        att_dv[nf] = att_d[(wn << 6) + (nf << 4) + fr];
    }
    #pragma unroll
    for (int m = 0; m < 4; ++m) {
        #pragma unroll
        for (int j = 0; j < 4; ++j) {
            float ps = acc[m][0][j] * att_sv[0] + acc[m][1][j] * att_sv[1]
                     + acc[m][2][j] * att_sv[2] + acc[m][3][j] * att_sv[3];
            float pd = acc[m][0][j] * att_dv[0] + acc[m][1][j] * att_dv[1]
                     + acc[m][2][j] * att_dv[2] + acc[m][3][j] * att_dv[3];
            ps += __shfl_xor(ps, 1, 64); pd += __shfl_xor(pd, 1, 64);
            ps += __shfl_xor(ps, 2, 64); pd += __shfl_xor(pd, 2, 64);
            ps += __shfl_xor(ps, 4, 64); pd += __shfl_xor(pd, 4, 64);
            ps += __shfl_xor(ps, 8, 64); pd += __shfl_xor(pd, 8, 64);
            if (fr == 0) {
                const int r_ = row0 + wm * 64 + m * 16 + fk * 4 + j;
                if (r_ < n) {
                    a_src[r_ * NH + wn] = ps;
                    a_dst[r_ * NH + wn] = pd;
                }
            }
        }
    }
}

// ---------------- K4a: per-1024-chunk partial sums ---------------------------------
__global__ __launch_bounds__(256) void scan_partial_kernel(const int* __restrict__ counts,
                                                           int* __restrict__ blockSums, int n) {
    __shared__ int sdata[256];
    const int b = blockIdx.x, t = threadIdx.x;
    const int base = b * 1024 + t * 4;
    int s = 0;
    #pragma unroll
    for (int j = 0; j < 4; ++j)
        if (base + j < n) s += counts[base + j];
    sdata[t] = s;
    __syncthreads();
    for (int off = 128; off > 0; off >>= 1) {
        if (t < off) sdata[t] += sdata[t + off];
        __syncthreads();
    }
    if (t == 0) blockSums[b] = sdata[0];
}

// ---------------- K4b: final scan (block-sum scan done redundantly per block) ------
__global__ __launch_bounds__(256) void scan_final_kernel(const int* __restrict__ counts,
                                                         const int* __restrict__ blockSums,
                                                         int* __restrict__ offsets, int n, int nb) {
    __shared__ int s[256];
    __shared__ int bs[256];
    const int b = blockIdx.x, t = threadIdx.x;
    int bv = (t < nb) ? blockSums[t] : 0;
    bs[t] = bv;
    __syncthreads();
    for (int d = 1; d < 256; d <<= 1) {
        int u = (t >= d) ? bs[t - d] : 0;
        __syncthreads();
        bs[t] += u;
        __syncthreads();
    }
    const int blockOff = (b > 0) ? bs[b - 1] : 0;

    const int base = b * 1024 + t * 4;
    int c[4];
    int tsum = 0;
    #pragma unroll
    for (int j = 0; j < 4; ++j) {
        c[j] = (base + j < n) ? counts[base + j] : 0;
        tsum += c[j];
    }
    s[t] = tsum;
    __syncthreads();
    for (int d = 1; d < 256; d <<= 1) {
        int u = (t >= d) ? s[t - d] : 0;
        __syncthreads();
        s[t] += u;
        __syncthreads();
    }
    int run = s[t] - tsum + blockOff;
    #pragma unroll
    for (int j = 0; j < 4; ++j) {
        if (base + j < n) {
            offsets[base + j] = run;
            run += c[j];
        }
    }
}

// ---------------- K5: scatter edges + fp16 weights — NO atomics (offsets + rank) ---
__global__ void scatter_kernel(const int* __restrict__ src, const int* __restrict__ dst,
                               const ushort_t* __restrict__ rank,
                               const float* __restrict__ a_src, const float* __restrict__ a_dst,
                               const int* __restrict__ offsets,
                               i32x4* __restrict__ erec, int E) {
    int stride = gridDim.x * blockDim.x;
    for (int e = blockIdx.x * blockDim.x + threadIdx.x; e < E; e += stride) {
        const int s = __builtin_nontemporal_load(&src[e]);
        const int d = __builtin_nontemporal_load(&dst[e]);
        const int r = rank[e];
        const float4 as = ((const float4*)a_src)[s];
        const float4 ad = ((const float4*)a_dst)[d];
        const float w0 = __expf(leaky02(as.x + ad.x));
        const float w1 = __expf(leaky02(as.y + ad.y));
        const float w2 = __expf(leaky02(as.z + ad.z));
        const float w3 = __expf(leaky02(as.w + ad.w));
        union { __half2 h; int i; } p01, p23;
        p01.h = __floats2half2_rn(w0, w1);
        p23.h = __floats2half2_rn(w2, w3);
        i32x4 rec;
        rec.x = s; rec.y = p01.i; rec.z = p23.i; rec.w = 0;
        const int pos = offsets[d] + r;
        __builtin_nontemporal_store(rec, &erec[pos]);
    }
}

// ---------------- K6: aggregation — wave per node, paired-edge 16B gathers ----------
__global__ __launch_bounds__(256) void aggregate_kernel(const ushort_t* __restrict__ xpb,
                                                        const float* __restrict__ a_src,
                                                        const float* __restrict__ a_dst,
                                                        const int* __restrict__ offsets,
                                                        const int* __restrict__ counts,
                                                        const i32x4* __restrict__ erec,
                                                        const float* __restrict__ bias,
                                                        float* __restrict__ out, int n) {
    const int i = (blockIdx.x << 2) + (threadIdx.x >> 6);
    if (i >= n) return;
    const int lane = threadIdx.x & 63;
    const int halfid = lane >> 5, sl = lane & 31;
    const int h = sl >> 3;                      // head for this lane's 8 cols
    const size_t colb = (size_t)sl << 3;        // col base (8 bf16 = 16 B)
    const int start = offsets[i];
    const int cnt = counts[i];
    const i32x4* recs = erec + start;

    float acc[8] = {};
    float den = 0.f;

    int e = 0;
    for (; e + 4 <= cnt; e += 4) {
        const i32x4 ra = recs[e + halfid];
        const i32x4 rb = recs[e + 2 + halfid];
        const ushort8 ua = *(const ushort8*)(xpb + (size_t)ra.x * FDIM + colb);
        const ushort8 ub = *(const ushort8*)(xpb + (size_t)rb.x * FDIM + colb);
        const float wa = recw(ra, h), wb = recw(rb, h);
        den += wa + wb;
        #pragma unroll
        for (int j = 0; j < 8; ++j) acc[j] = fmaf(wa, bf2f(ua[j]), acc[j]);
        #pragma unroll
        for (int j = 0; j < 8; ++j) acc[j] = fmaf(wb, bf2f(ub[j]), acc[j]);
    }
    for (; e < cnt; e += 2) {                   // tail: 1..3 edges
        const int idx = e + halfid;
        const int cidx = idx < cnt ? idx : cnt - 1;
        const i32x4 r = recs[cidx];
        const ushort8 u = *(const ushort8*)(xpb + (size_t)r.x * FDIM + colb);
        const float wv = idx < cnt ? recw(r, h) : 0.f;
        den += wv;
        #pragma unroll
        for (int j = 0; j < 8; ++j) acc[j] = fmaf(wv, bf2f(u[j]), acc[j]);
    }
    // self-loop: half0 alone covers all 256 cols
    if (halfid == 0) {
        const float ws = __expf(leaky02(a_src[i * NH + h] + a_dst[i * NH + h]));
        const ushort8 u = *(const ushort8*)(xpb + (size_t)i * FDIM + colb);
        den += ws;
        #pragma unroll
        for (int j = 0; j < 8; ++j) acc[j] = fmaf(ws, bf2f(u[j]), acc[j]);
    }
    // cross-half combine
    den += __shfl_xor(den, 32, 64);
    #pragma unroll
    for (int j = 0; j < 8; ++j) acc[j] += __shfl_xor(acc[j], 32, 64);

    const float inv = 1.0f / den;
    const int c0 = (sl << 3) + (halfid << 2);   // this lane writes 4 floats
    const float4 b4 = *(const float4*)(bias + c0);
    const int jb = halfid << 2;
    f32x4 v;
    v.x = acc[jb + 0] * inv + b4.x;
    v.y = acc[jb + 1] * inv + b4.y;
    v.z = acc[jb + 2] * inv + b4.z;
    v.w = acc[jb + 3] * inv + b4.w;
    v.x = v.x > 0.f ? v.x : (__expf(v.x) - 1.f);
    v.y = v.y > 0.f ? v.y : (__expf(v.y) - 1.f);
    v.z = v.z > 0.f ? v.z : (__expf(v.z) - 1.f);
    v.w = v.w > 0.f ? v.w : (__expf(v.w) - 1.f);
    *(f32x4*)(out + (size_t)i * FDIM + c0) = v;
}

// ---------------- launch -----------------------------------------------------------
extern "C" void kernel_launch(void* const* d_in, const int* in_sizes, int n_in,
                              void* d_out, int out_size, void* d_ws, size_t ws_size,
                              hipStream_t stream) {
    const float* x       = (const float*)d_in[0];
    const int*   ei      = (const int*)d_in[1];
    const float* W       = (const float*)d_in[2];
    const float* att_s   = (const float*)d_in[3];
    const float* att_d   = (const float*)d_in[4];
    const float* bias    = (const float*)d_in[5];
    float* out = (float*)d_out;

    const int n = in_sizes[0] / FDIM;   // 100000
    const int E = in_sizes[1] / 2;      // 1600000
    const int* src = ei;
    const int* dst = ei + E;

    char* ws = (char*)d_ws;
    size_t off = 0;
    auto alloc = [&](size_t bytes) -> void* {
        void* p = ws + off;
        off = (off + bytes + 255) & ~(size_t)255;
        return p;
    };
    ushort_t* xpb  = (ushort_t*)alloc((size_t)n * FDIM * sizeof(ushort_t));
    ushort_t* xb   = (ushort_t*)alloc((size_t)n * FDIM * sizeof(ushort_t));
    float* a_src   = (float*)alloc((size_t)n * NH * sizeof(float));
    float* a_dst   = (float*)alloc((size_t)n * NH * sizeof(float));
    int* counts    = (int*)alloc((size_t)n * sizeof(int));
    int* offsets   = (int*)alloc((size_t)n * sizeof(int));
    int* blockSums = (int*)alloc(256 * sizeof(int));
    ushort_t* rank = (ushort_t*)alloc((size_t)E * sizeof(ushort_t));
    i32x4* erec    = (i32x4*)alloc((size_t)E * sizeof(i32x4));
    ushort_t* Wbf  = (ushort_t*)alloc((size_t)FDIM * FDIM * sizeof(ushort_t));
    (void)ws_size;

    hipMemsetAsync(counts, 0, (size_t)n * sizeof(int), stream);

    wprep_kernel<<<256, 256, 0, stream>>>(W, Wbf);
    xprep_kernel<<<2048, 256, 0, stream>>>(x, xb, n, dst, counts, rank, E);
    gemm_xp_kernel<<<(n + 127) / 128, 512, 0, stream>>>(xb, Wbf, att_s, att_d, xpb, a_src, a_dst, n);
    const int nb = (n + 1023) / 1024;   // 98
    scan_partial_kernel<<<nb, 256, 0, stream>>>(counts, blockSums, n);
    scan_final_kernel<<<nb, 256, 0, stream>>>(counts, blockSums, offsets, n, nb);
    scatter_kernel<<<2048, 256, 0, stream>>>(src, dst, rank, a_src, a_dst, offsets, erec, E);
    aggregate_kernel<<<(n + 3) / 4, 256, 0, stream>>>(xpb, a_src, a_dst, offsets, counts, erec,
                                                      bias, out, n);
}

// Round 20
// 320.282 us; speedup vs baseline: 1.0869x; 1.0869x over previous
//
#include <hip/hip_runtime.h>
#include <hip/hip_fp16.h>

#define FDIM 256   // H*C = 4*64
#define NH 4

typedef float f32x4 __attribute__((ext_vector_type(4)));
typedef int   i32x4 __attribute__((ext_vector_type(4)));
typedef short short8v __attribute__((ext_vector_type(8)));
typedef unsigned short ushort_t;
typedef unsigned short ushort8 __attribute__((ext_vector_type(8)));

__device__ __forceinline__ float leaky02(float v) { return v > 0.0f ? v : 0.2f * v; }

__device__ __forceinline__ ushort_t f2bf(float f) {
    union { float f; unsigned int u; } v; v.f = f;
    unsigned int u = v.u + 0x7FFFu + ((v.u >> 16) & 1u);   // RNE
    return (ushort_t)(u >> 16);
}

__device__ __forceinline__ float bf2f(ushort_t u) {
    union { float f; unsigned int u; } v;
    v.u = ((unsigned int)u) << 16;
    return v.f;
}

__device__ __forceinline__ void gload_lds16(const void* g, void* lds) {
    __builtin_amdgcn_global_load_lds((const __attribute__((address_space(1))) unsigned int*)g,
                                     (__attribute__((address_space(3))) unsigned int*)lds, 16, 0, 0);
}

// unpack fp16 weight for head h from edge record
__device__ __forceinline__ float recw(const i32x4& r, int h) {
    unsigned v = (h < 2) ? (unsigned)r.y : (unsigned)r.z;
    unsigned bits = (h & 1) ? (v >> 16) : (v & 0xFFFFu);
    __half_raw hr; hr.x = (unsigned short)bits;
    return __half2float(*reinterpret_cast<__half*>(&hr));
}

// ---------------- K0: W (fp32 [256][256]) -> Wbf bf16 fragment-linear -------------
__global__ __launch_bounds__(256) void wprep_kernel(const float* __restrict__ W,
                                                    ushort_t* __restrict__ Wbf) {
    const int k = blockIdx.x;
    const int col = threadIdx.x;
    Wbf[(((size_t)(k >> 3) * 256 + col) << 3) + (k & 7)] = f2bf(W[(size_t)k * 256 + col]);
}

// ---------------- K1: xpb = bf16(x @ W) + attention dots + degree/rank histogram ---
// 512 threads (8 waves, wm=w>>2 in {0,1}, wn=w&3 = HEAD), BM=128, BN=256, BK=32.
__global__ __launch_bounds__(512) void gemm_xp_kernel(const float* __restrict__ x,
                                                      const ushort_t* __restrict__ Wbf,
                                                      const float* __restrict__ att_s,
                                                      const float* __restrict__ att_d,
                                                      ushort_t* __restrict__ xpb,
                                                      float* __restrict__ a_src,
                                                      float* __restrict__ a_dst, int n,
                                                      const int* __restrict__ dst,
                                                      int* __restrict__ counts,
                                                      ushort_t* __restrict__ rank, int E) {
    __shared__ ushort_t a_lds[4096];   // [kblk 0..3][row 0..127][8]   8 KB
    __shared__ ushort_t b_lds[8192];   // [kblk 0..3][col 0..255][8]  16 KB
    const int t = threadIdx.x;

    // --- fused degree histogram + rank recording (atomic return value = rank) ---
    {
        const int per = (E + gridDim.x - 1) / gridDim.x;
        const int lo = blockIdx.x * per;
        const int hi = min(lo + per, E);
        for (int e = lo + t; e < hi; e += 512) {
            const int d = __builtin_nontemporal_load(&dst[e]);
            rank[e] = (ushort_t)atomicAdd(&counts[d], 1);
        }
    }

    const int w = t >> 6, l = t & 63;
    const int wm = w >> 2, wn = w & 3;
    const int row0 = blockIdx.x << 7;
    const int fr = l & 15, fk = l >> 4;

    const int arow = t & 127, akb = t >> 7;
    int grow = row0 + arow;
    if (grow >= n) grow = n - 1;
    const float* aptr = x + (size_t)grow * FDIM + (akb << 3);

    f32x4 acc[4][4] = {};

    for (int s = 0; s < 8; ++s) {
        float4 v0 = *(const float4*)(aptr + s * 32);
        float4 v1 = *(const float4*)(aptr + s * 32 + 4);
        ushort8 u;
        u[0]=f2bf(v0.x); u[1]=f2bf(v0.y); u[2]=f2bf(v0.z); u[3]=f2bf(v0.w);
        u[4]=f2bf(v1.x); u[5]=f2bf(v1.y); u[6]=f2bf(v1.z); u[7]=f2bf(v1.w);

        if (s) __syncthreads();

        *(ushort8*)&a_lds[(((size_t)akb << 7) + arow) << 3] = u;
        gload_lds16(Wbf + (size_t)s * 8192 + ((size_t)t << 3), (char*)b_lds + (w << 10));
        gload_lds16(Wbf + (size_t)s * 8192 + ((size_t)(t + 512) << 3), (char*)b_lds + 8192 + (w << 10));
        __syncthreads();

        short8v af[4], bfv[4];
        #pragma unroll
        for (int m = 0; m < 4; ++m)
            af[m] = *(const short8v*)&a_lds[(((size_t)fk << 7) + wm * 64 + m * 16 + fr) << 3];
        #pragma unroll
        for (int nf = 0; nf < 4; ++nf)
            bfv[nf] = *(const short8v*)&b_lds[(((size_t)fk << 8) + wn * 64 + nf * 16 + fr) << 3];
        #pragma unroll
        for (int m = 0; m < 4; ++m)
            #pragma unroll
            for (int nf = 0; nf < 4; ++nf)
                acc[m][nf] = __builtin_amdgcn_mfma_f32_16x16x32_bf16(af[m], bfv[nf], acc[m][nf], 0, 0, 0);
    }

    // ---- epilogue 1: bf16 store ----
    #pragma unroll
    for (int m = 0; m < 4; ++m) {
        const int r_ = row0 + wm * 64 + m * 16 + fk * 4;
        #pragma unroll
        for (int nf = 0; nf < 4; ++nf) {
            const int c_ = wn * 64 + nf * 16 + fr;
            #pragma unroll
            for (int j = 0; j < 4; ++j)
                if (r_ + j < n)
                    xpb[(size_t)(r_ + j) * FDIM + c_] = f2bf(acc[m][nf][j]);
        }
    }

    // ---- epilogue 2: fused fp32 attention dots (wave wn == head wn) ----
    float att_sv[4], att_dv[4];
    #pragma unroll
    for (int nf = 0; nf < 4; ++nf) {
        att_sv[nf] = att_s[(wn << 6) + (nf << 4) + fr];
        att_dv[nf] = att_d[(wn << 6) + (nf << 4) + fr];
    }
    #pragma unroll
    for (int m = 0; m < 4; ++m) {
        #pragma unroll
        for (int j = 0; j < 4; ++j) {
            float ps = acc[m][0][j] * att_sv[0] + acc[m][1][j] * att_sv[1]
                     + acc[m][2][j] * att_sv[2] + acc[m][3][j] * att_sv[3];
            float pd = acc[m][0][j] * att_dv[0] + acc[m][1][j] * att_dv[1]
                     + acc[m][2][j] * att_dv[2] + acc[m][3][j] * att_dv[3];
            ps += __shfl_xor(ps, 1, 64); pd += __shfl_xor(pd, 1, 64);
            ps += __shfl_xor(ps, 2, 64); pd += __shfl_xor(pd, 2, 64);
            ps += __shfl_xor(ps, 4, 64); pd += __shfl_xor(pd, 4, 64);
            ps += __shfl_xor(ps, 8, 64); pd += __shfl_xor(pd, 8, 64);
            if (fr == 0) {
                const int r_ = row0 + wm * 64 + m * 16 + fk * 4 + j;
                if (r_ < n) {
                    a_src[r_ * NH + wn] = ps;
                    a_dst[r_ * NH + wn] = pd;
                }
            }
        }
    }
}

// ---------------- K4a: per-1024-chunk partial sums ---------------------------------
__global__ __launch_bounds__(256) void scan_partial_kernel(const int* __restrict__ counts,
                                                           int* __restrict__ blockSums, int n) {
    __shared__ int sdata[256];
    const int b = blockIdx.x, t = threadIdx.x;
    const int base = b * 1024 + t * 4;
    int s = 0;
    #pragma unroll
    for (int j = 0; j < 4; ++j)
        if (base + j < n) s += counts[base + j];
    sdata[t] = s;
    __syncthreads();
    for (int off = 128; off > 0; off >>= 1) {
        if (t < off) sdata[t] += sdata[t + off];
        __syncthreads();
    }
    if (t == 0) blockSums[b] = sdata[0];
}

// ---------------- K4b: final scan (block-sum scan done redundantly per block) ------
__global__ __launch_bounds__(256) void scan_final_kernel(const int* __restrict__ counts,
                                                         const int* __restrict__ blockSums,
                                                         int* __restrict__ offsets, int n, int nb) {
    __shared__ int s[256];
    __shared__ int bs[256];
    const int b = blockIdx.x, t = threadIdx.x;
    int bv = (t < nb) ? blockSums[t] : 0;
    bs[t] = bv;
    __syncthreads();
    for (int d = 1; d < 256; d <<= 1) {
        int u = (t >= d) ? bs[t - d] : 0;
        __syncthreads();
        bs[t] += u;
        __syncthreads();
    }
    const int blockOff = (b > 0) ? bs[b - 1] : 0;

    const int base = b * 1024 + t * 4;
    int c[4];
    int tsum = 0;
    #pragma unroll
    for (int j = 0; j < 4; ++j) {
        c[j] = (base + j < n) ? counts[base + j] : 0;
        tsum += c[j];
    }
    s[t] = tsum;
    __syncthreads();
    for (int d = 1; d < 256; d <<= 1) {
        int u = (t >= d) ? s[t - d] : 0;
        __syncthreads();
        s[t] += u;
        __syncthreads();
    }
    int run = s[t] - tsum + blockOff;
    #pragma unroll
    for (int j = 0; j < 4; ++j) {
        if (base + j < n) {
            offsets[base + j] = run;
            run += c[j];
        }
    }
}

// ---------------- K5: scatter edges + fp16 weights — NO atomics (offsets + rank) ---
__global__ void scatter_kernel(const int* __restrict__ src, const int* __restrict__ dst,
                               const ushort_t* __restrict__ rank,
                               const float* __restrict__ a_src, const float* __restrict__ a_dst,
                               const int* __restrict__ offsets,
                               i32x4* __restrict__ erec, int E) {
    int stride = gridDim.x * blockDim.x;
    for (int e = blockIdx.x * blockDim.x + threadIdx.x; e < E; e += stride) {
        const int s = __builtin_nontemporal_load(&src[e]);
        const int d = __builtin_nontemporal_load(&dst[e]);
        const int r = rank[e];
        const float4 as = ((const float4*)a_src)[s];
        const float4 ad = ((const float4*)a_dst)[d];
        const float w0 = __expf(leaky02(as.x + ad.x));
        const float w1 = __expf(leaky02(as.y + ad.y));
        const float w2 = __expf(leaky02(as.z + ad.z));
        const float w3 = __expf(leaky02(as.w + ad.w));
        union { __half2 h; int i; } p01, p23;
        p01.h = __floats2half2_rn(w0, w1);
        p23.h = __floats2half2_rn(w2, w3);
        i32x4 rec;
        rec.x = s; rec.y = p01.i; rec.z = p23.i; rec.w = 0;
        const int pos = offsets[d] + r;
        __builtin_nontemporal_store(rec, &erec[pos]);
    }
}

// ---------------- K6: aggregation — wave per node, paired-edge 16B gathers ----------
__global__ __launch_bounds__(256) void aggregate_kernel(const ushort_t* __restrict__ xpb,
                                                        const float* __restrict__ a_src,
                                                        const float* __restrict__ a_dst,
                                                        const int* __restrict__ offsets,
                                                        const int* __restrict__ counts,
                                                        const i32x4* __restrict__ erec,
                                                        const float* __restrict__ bias,
                                                        float* __restrict__ out, int n) {
    const int i = (blockIdx.x << 2) + (threadIdx.x >> 6);
    if (i >= n) return;
    const int lane = threadIdx.x & 63;
    const int halfid = lane >> 5, sl = lane & 31;
    const int h = sl >> 3;                      // head for this lane's 8 cols
    const size_t colb = (size_t)sl << 3;        // col base (8 bf16 = 16 B)
    const int start = offsets[i];
    const int cnt = counts[i];
    const i32x4* recs = erec + start;

    float acc[8] = {};
    float den = 0.f;

    int e = 0;
    for (; e + 4 <= cnt; e += 4) {
        const i32x4 ra = recs[e + halfid];
        const i32x4 rb = recs[e + 2 + halfid];
        const ushort8 ua = *(const ushort8*)(xpb + (size_t)ra.x * FDIM + colb);
        const ushort8 ub = *(const ushort8*)(xpb + (size_t)rb.x * FDIM + colb);
        const float wa = recw(ra, h), wb = recw(rb, h);
        den += wa + wb;
        #pragma unroll
        for (int j = 0; j < 8; ++j) acc[j] = fmaf(wa, bf2f(ua[j]), acc[j]);
        #pragma unroll
        for (int j = 0; j < 8; ++j) acc[j] = fmaf(wb, bf2f(ub[j]), acc[j]);
    }
    for (; e < cnt; e += 2) {                   // tail: 1..3 edges
        const int idx = e + halfid;
        const int cidx = idx < cnt ? idx : cnt - 1;
        const i32x4 r = recs[cidx];
        const ushort8 u = *(const ushort8*)(xpb + (size_t)r.x * FDIM + colb);
        const float wv = idx < cnt ? recw(r, h) : 0.f;
        den += wv;
        #pragma unroll
        for (int j = 0; j < 8; ++j) acc[j] = fmaf(wv, bf2f(u[j]), acc[j]);
    }
    // self-loop: half0 alone covers all 256 cols
    if (halfid == 0) {
        const float ws = __expf(leaky02(a_src[i * NH + h] + a_dst[i * NH + h]));
        const ushort8 u = *(const ushort8*)(xpb + (size_t)i * FDIM + colb);
        den += ws;
        #pragma unroll
        for (int j = 0; j < 8; ++j) acc[j] = fmaf(ws, bf2f(u[j]), acc[j]);
    }
    // cross-half combine
    den += __shfl_xor(den, 32, 64);
    #pragma unroll
    for (int j = 0; j < 8; ++j) acc[j] += __shfl_xor(acc[j], 32, 64);

    const float inv = 1.0f / den;
    const int c0 = (sl << 3) + (halfid << 2);   // this lane writes 4 floats
    const float4 b4 = *(const float4*)(bias + c0);
    const int jb = halfid << 2;
    f32x4 v;
    v.x = acc[jb + 0] * inv + b4.x;
    v.y = acc[jb + 1] * inv + b4.y;
    v.z = acc[jb + 2] * inv + b4.z;
    v.w = acc[jb + 3] * inv + b4.w;
    v.x = v.x > 0.f ? v.x : (__expf(v.x) - 1.f);
    v.y = v.y > 0.f ? v.y : (__expf(v.y) - 1.f);
    v.z = v.z > 0.f ? v.z : (__expf(v.z) - 1.f);
    v.w = v.w > 0.f ? v.w : (__expf(v.w) - 1.f);
    *(f32x4*)(out + (size_t)i * FDIM + c0) = v;
}

// ---------------- launch -----------------------------------------------------------
extern "C" void kernel_launch(void* const* d_in, const int* in_sizes, int n_in,
                              void* d_out, int out_size, void* d_ws, size_t ws_size,
                              hipStream_t stream) {
    const float* x       = (const float*)d_in[0];
    const int*   ei      = (const int*)d_in[1];
    const float* W       = (const float*)d_in[2];
    const float* att_s   = (const float*)d_in[3];
    const float* att_d   = (const float*)d_in[4];
    const float* bias    = (const float*)d_in[5];
    float* out = (float*)d_out;

    const int n = in_sizes[0] / FDIM;   // 100000
    const int E = in_sizes[1] / 2;      // 1600000
    const int* src = ei;
    const int* dst = ei + E;

    char* ws = (char*)d_ws;
    size_t off = 0;
    auto alloc = [&](size_t bytes) -> void* {
        void* p = ws + off;
        off = (off + bytes + 255) & ~(size_t)255;
        return p;
    };
    ushort_t* xpb  = (ushort_t*)alloc((size_t)n * FDIM * sizeof(ushort_t));
    float* a_src   = (float*)alloc((size_t)n * NH * sizeof(float));
    float* a_dst   = (float*)alloc((size_t)n * NH * sizeof(float));
    int* counts    = (int*)alloc((size_t)n * sizeof(int));
    int* offsets   = (int*)alloc((size_t)n * sizeof(int));
    int* blockSums = (int*)alloc(256 * sizeof(int));
    ushort_t* rank = (ushort_t*)alloc((size_t)E * sizeof(ushort_t));
    i32x4* erec    = (i32x4*)alloc((size_t)E * sizeof(i32x4));
    ushort_t* Wbf  = (ushort_t*)alloc((size_t)FDIM * FDIM * sizeof(ushort_t));
    (void)ws_size;

    hipMemsetAsync(counts, 0, (size_t)n * sizeof(int), stream);

    wprep_kernel<<<256, 256, 0, stream>>>(W, Wbf);
    gemm_xp_kernel<<<(n + 127) / 128, 512, 0, stream>>>(x, Wbf, att_s, att_d, xpb, a_src, a_dst, n,
                                                        dst, counts, rank, E);
    const int nb = (n + 1023) / 1024;   // 98
    scan_partial_kernel<<<nb, 256, 0, stream>>>(counts, blockSums, n);
    scan_final_kernel<<<nb, 256, 0, stream>>>(counts, blockSums, offsets, n, nb);
    scatter_kernel<<<2048, 256, 0, stream>>>(src, dst, rank, a_src, a_dst, offsets, erec, E);
    aggregate_kernel<<<(n + 3) / 4, 256, 0, stream>>>(xpb, a_src, a_dst, offsets, counts, erec,
                                                      bias, out, n);
}